// Round 8
// baseline (1367.640 us; speedup 1.0000x reference)
//
#include <hip/hip_runtime.h>
#include <hip/hip_bf16.h>

#define M_TOK 16384
#define K_DIM 1024
#define E_NUM 8
#define N_DIM 5632
#define HALF_N 2816
#define TOPK 2
#define NPAIR (M_TOK * TOPK)     // 32768
#define BM 128
#define BK 64
#define BH1 128                  // gemm1 h-cols per block
#define BN2 256                  // gemm2 k-cols per block
#define NDESC (NPAIR / BM + E_NUM)  // 264
#define NHB1 (HALF_N / BH1)      // 22
#define NNB2 (K_DIM / BN2)       // 4

typedef short s16x4 __attribute__((ext_vector_type(4)));
typedef short s16x8 __attribute__((ext_vector_type(8)));
typedef float f32x4 __attribute__((ext_vector_type(4)));
typedef float f32x16 __attribute__((ext_vector_type(16)));

__device__ __forceinline__ short f2bf(float f) {
  union { __hip_bfloat16 h; short s; } c;
  c.h = __float2bfloat16(f);
  return c.s;
}

__device__ __forceinline__ float bf2f(unsigned short s) {
  union { float f; unsigned u; } c;
  c.u = ((unsigned)s) << 16;
  return c.f;
}

__device__ __forceinline__ void gload_lds16(const void* g, void* l) {
  __builtin_amdgcn_global_load_lds(
      (const __attribute__((address_space(1))) unsigned int*)g,
      (__attribute__((address_space(3))) unsigned int*)l, 16, 0, 0);
}

// bijective XCD-aware work remap (m204): consecutive work indices land on one XCD
__device__ __forceinline__ int xcd_work(int bid, int nwg) {
  const int xcd = bid & 7, loc = bid >> 3;
  const int q = nwg >> 3, r = nwg & 7;
  return (xcd < r ? xcd * (q + 1) : r * (q + 1) + (xcd - r) * q) + loc;
}

// ---------------- conversion ----------------
__global__ void cvt_f32_bf16_k(const float4* __restrict__ src,
                               s16x4* __restrict__ dst, int n4) {
  int i = blockIdx.x * blockDim.x + threadIdx.x;
  int stride = gridDim.x * blockDim.x;
  for (; i < n4; i += stride) {
    float4 f = src[i];
    s16x4 o = { f2bf(f.x), f2bf(f.y), f2bf(f.z), f2bf(f.w) };
    dst[i] = o;
  }
}

// ---------------- routing (two-level, ~1k global atomics total) ----------------
__global__ void moe_count(const int* __restrict__ ids, int* __restrict__ cnt) {
  const int p = blockIdx.x * 256 + threadIdx.x;
  const int e = ids[p];
  const int lane = threadIdx.x & 63;
  __shared__ int h[E_NUM];
  if (threadIdx.x < E_NUM) h[threadIdx.x] = 0;
  __syncthreads();
#pragma unroll
  for (int ex = 0; ex < E_NUM; ++ex) {
    unsigned long long m = __ballot(e == ex);
    if (lane == 0 && m) atomicAdd(&h[ex], __popcll(m));
  }
  __syncthreads();
  if (threadIdx.x < E_NUM) atomicAdd(&cnt[threadIdx.x], h[threadIdx.x]);
}

__global__ void moe_build(const int* __restrict__ cnt, int* __restrict__ offs,
                          int4* __restrict__ desc) {
  if (blockIdx.x == 0 && threadIdx.x == 0) {
    int o = 0, d = 0;
    for (int e = 0; e < E_NUM; ++e) {
      offs[e] = o;
      int end = o + cnt[e];
      for (int s = o; s < end; s += BM) desc[d++] = make_int4(e, s, end, 0);
      o = end;
    }
    offs[E_NUM] = o;
    while (d < NDESC) desc[d++] = make_int4(-1, 0, 0, 0);
  }
}

__global__ void moe_scatter(const int* __restrict__ ids, const float* __restrict__ tw,
                            const int* __restrict__ offs, int* __restrict__ fill,
                            int* __restrict__ tok, float* __restrict__ wgt,
                            int* __restrict__ inv) {
  const int p = blockIdx.x * 256 + threadIdx.x;
  const int e = ids[p];
  const int lane = threadIdx.x & 63;
  const int w = threadIdx.x >> 6;  // 0..3
  __shared__ int wcnt[4][E_NUM];
  __shared__ int wpre[4][E_NUM];
  __shared__ int base[E_NUM];
  const unsigned long long lt = (1ull << lane) - 1ull;
  int myrank = 0;
#pragma unroll
  for (int ex = 0; ex < E_NUM; ++ex) {
    unsigned long long m = __ballot(e == ex);
    if (e == ex) myrank = (int)__popcll(m & lt);
    if (lane == 0) wcnt[w][ex] = (int)__popcll(m);
  }
  __syncthreads();
  if (threadIdx.x < E_NUM) {
    const int ex = threadIdx.x;
    int s = 0;
#pragma unroll
    for (int ww = 0; ww < 4; ++ww) { wpre[ww][ex] = s; s += wcnt[ww][ex]; }
    base[ex] = atomicAdd(&fill[ex], s);
  }
  __syncthreads();
  const int pos = offs[e] + base[e] + wpre[w][e] + myrank;
  tok[pos] = p >> 1;
  wgt[pos] = tw[p];
  inv[p] = pos;
}

// gather hidden rows into expert-sorted order, fp32 -> bf16
__global__ void moe_gather(const float* __restrict__ hs, const int* __restrict__ tok,
                           unsigned short* __restrict__ hsb) {
  const int pos = blockIdx.x;
  const int m = tok[pos];
  const int t = threadIdx.x;  // 128 threads * 8 elems = 1024
  const float4* s = (const float4*)(hs + (size_t)m * K_DIM) + t * 2;
  const float4 a = s[0], b = s[1];
  s16x8 o = { f2bf(a.x), f2bf(a.y), f2bf(a.z), f2bf(a.w),
              f2bf(b.x), f2bf(b.y), f2bf(b.z), f2bf(b.w) };
  *(s16x8*)(hsb + (size_t)pos * K_DIM + t * 8) = o;
}

// ---------------- GEMM1: h2 = silu(A@Wg^T) * (A@Wu^T) ----------------
// r7 skeleton (2-barrier, gload_lds, 8 waves) but:
//  * mfma_f32_32x32x16_bf16 (16 MFMA/tile/wave instead of 32; 15% faster pipe)
//  * granule-column-major LDS (granule = chunk*128 + row) -> conflict-free
//    reads with NO swizzle (source permutation defines layout; rule 21).
// Waves: wr=wid>>2 (64-row group), wc=wid&3 (32-col group of G and U).
__launch_bounds__(512)
__global__ void moe_gemm1(const unsigned short* __restrict__ hsb,
                          const unsigned short* __restrict__ w1b,
                          const int4* __restrict__ desc,
                          unsigned short* __restrict__ h2) {
  const int work = xcd_work(blockIdx.x, NHB1 * NDESC);
  const int di = work / NHB1;
  const int hb = work - di * NHB1;
  const int4 d = desc[di];
  const int e = d.x;
  if (e < 0) return;
  const int pos0 = d.y, eend = d.z;
  const int h0 = hb * BH1;

  __shared__ __align__(16) unsigned short As[BM * BK];    // 16 KB, [chunk8][row128][8]
  __shared__ __align__(16) unsigned short Gs[BH1 * BK];   // 16 KB
  __shared__ __align__(16) unsigned short Us[BH1 * BK];   // 16 KB

  const int tid = threadIdx.x;
  const int lane = tid & 63;
  const int wid = tid >> 6;     // 0..7
  const int wr = wid >> 2;      // 0..1 (64-row group)
  const int wc = wid & 3;       // 0..3 (32-col group)
  const int la = lane & 31;
  const int hi = lane >> 5;

  // staging source pointers: thread covers granules g = c*512 + tid, c in {0,1}
  // row = tid & 127, chunk = c*4 + (tid>>7); src k-offset = chunk*8
  const int srow = tid & 127;
  const int chA = tid >> 7;     // chunk base for c=0 (c=1 adds 4)
  const unsigned short* Ap = hsb + (size_t)(pos0 + srow) * K_DIM + chA * 8;
  const unsigned short* Gp = w1b + ((size_t)e * N_DIM + h0 + srow) * K_DIM + chA * 8;
  const unsigned short* Up = Gp + (size_t)HALF_N * K_DIM;

  f32x16 accg[2], accu[2];
#pragma unroll
  for (int i = 0; i < 2; ++i) {
#pragma unroll
    for (int r = 0; r < 16; ++r) { accg[i][r] = 0.f; accu[i][r] = 0.f; }
  }

  for (int kt = 0; kt < K_DIM / BK; ++kt) {
    const int k0 = kt * BK;
#pragma unroll
    for (int c = 0; c < 2; ++c) {
      const int goff = (c * 512 + tid) * 8;   // LDS granule offset (shorts)
      const int koff = k0 + c * 32;           // c adds 4 chunks = 32 shorts
      gload_lds16(Ap + koff, &As[goff]);
      gload_lds16(Gp + koff, &Gs[goff]);
      gload_lds16(Up + koff, &Us[goff]);
    }
    __syncthreads();
#pragma unroll
    for (int ks = 0; ks < 4; ++ks) {
      const int cb = ((ks * 2 + hi) << 7);    // granule row-base for this k-step
      s16x8 af0 = *(const s16x8*)&As[(cb + 64 * wr + la) * 8];
      s16x8 af1 = *(const s16x8*)&As[(cb + 64 * wr + 32 + la) * 8];
      s16x8 gf  = *(const s16x8*)&Gs[(cb + 32 * wc + la) * 8];
      s16x8 uf  = *(const s16x8*)&Us[(cb + 32 * wc + la) * 8];
      accg[0] = __builtin_amdgcn_mfma_f32_32x32x16_bf16(af0, gf, accg[0], 0, 0, 0);
      accu[0] = __builtin_amdgcn_mfma_f32_32x32x16_bf16(af0, uf, accu[0], 0, 0, 0);
      accg[1] = __builtin_amdgcn_mfma_f32_32x32x16_bf16(af1, gf, accg[1], 0, 0, 0);
      accu[1] = __builtin_amdgcn_mfma_f32_32x32x16_bf16(af1, uf, accu[1], 0, 0, 0);
    }
    __syncthreads();
  }

  // C/D layout (m74/m101): col = lane&31, row = (reg&3) + 8*(reg>>2) + 4*(lane>>5)
  const int vlim = eend - pos0;
#pragma unroll
  for (int i = 0; i < 2; ++i) {
#pragma unroll
    for (int r = 0; r < 16; ++r) {
      const int row = 64 * wr + 32 * i + (r & 3) + 8 * (r >> 2) + 4 * hi;
      if (row < vlim) {
        const float g = accg[i][r];
        const float u = accu[i][r];
        const float sg = g / (1.0f + __expf(-g));
        h2[(size_t)(pos0 + row) * HALF_N + h0 + 32 * wc + la] =
            (unsigned short)f2bf(sg * u);
      }
    }
  }
}

// ---------------- GEMM2: opair[pos] = wgt[pos] * (h2[pos] @ W2^T) ----------------
// same conversion: 32x32x16 MFMA + granule-column-major LDS, r7 sync skeleton.
// 128x256 tile, 8 waves (wr 64-row x wc 64-col groups), per-wave 64x64.
__launch_bounds__(512)
__global__ void moe_gemm2(const unsigned short* __restrict__ h2,
                          const unsigned short* __restrict__ w2b,
                          const int4* __restrict__ desc,
                          const float* __restrict__ wgt,
                          unsigned short* __restrict__ opair) {
  const int work = xcd_work(blockIdx.x, NNB2 * NDESC);
  const int di = work >> 2;
  const int nb = work & 3;
  const int4 d = desc[di];
  const int e = d.x;
  if (e < 0) return;
  const int pos0 = d.y, eend = d.z;
  const int n0 = nb * BN2;

  __shared__ __align__(16) unsigned short As[BM * BK];    // 16 KB, [chunk8][row128][8]
  __shared__ __align__(16) unsigned short Bs[BN2 * BK];   // 32 KB, [chunk8][row256][8]

  const int tid = threadIdx.x;
  const int lane = tid & 63;
  const int wid = tid >> 6;     // 0..7
  const int wr = wid >> 2;      // 0..1 (64-row group)
  const int wc = wid & 3;       // 0..3 (64-col group)
  const int la = lane & 31;
  const int hi = lane >> 5;

  // A staging: g = c*512+tid (c 0..1): row = tid&127, chunk = c*4 + (tid>>7)
  const int sarow = tid & 127;
  const int chA = tid >> 7;
  const unsigned short* Ap = h2 + (size_t)(pos0 + sarow) * HALF_N + chA * 8;
  // B staging: g = c*512+tid (c 0..3): row = tid&255, chunk = c*2 + (tid>>8)
  const int sbrow = tid & 255;
  const int chB = tid >> 8;
  const unsigned short* Bp = w2b + ((size_t)e * K_DIM + n0 + sbrow) * HALF_N + chB * 8;

  f32x16 acc[2][2];
#pragma unroll
  for (int i = 0; i < 2; ++i)
#pragma unroll
    for (int j = 0; j < 2; ++j)
#pragma unroll
      for (int r = 0; r < 16; ++r) acc[i][j][r] = 0.f;

  for (int ht = 0; ht < HALF_N / BK; ++ht) {   // 44
    const int k0 = ht * BK;
#pragma unroll
    for (int c = 0; c < 2; ++c) {
      gload_lds16(Ap + k0 + c * 32, &As[(c * 512 + tid) * 8]);
    }
#pragma unroll
    for (int c = 0; c < 4; ++c) {
      gload_lds16(Bp + k0 + c * 16, &Bs[(c * 512 + tid) * 8]);  // c adds 2 chunks
    }
    __syncthreads();
#pragma unroll
    for (int ks = 0; ks < 4; ++ks) {
      const int cbA = ((ks * 2 + hi) << 7);
      const int cbB = ((ks * 2 + hi) << 8);
      s16x8 af0 = *(const s16x8*)&As[(cbA + 64 * wr + la) * 8];
      s16x8 af1 = *(const s16x8*)&As[(cbA + 64 * wr + 32 + la) * 8];
      s16x8 bf0 = *(const s16x8*)&Bs[(cbB + 64 * wc + la) * 8];
      s16x8 bf1 = *(const s16x8*)&Bs[(cbB + 64 * wc + 32 + la) * 8];
      acc[0][0] = __builtin_amdgcn_mfma_f32_32x32x16_bf16(af0, bf0, acc[0][0], 0, 0, 0);
      acc[0][1] = __builtin_amdgcn_mfma_f32_32x32x16_bf16(af0, bf1, acc[0][1], 0, 0, 0);
      acc[1][0] = __builtin_amdgcn_mfma_f32_32x32x16_bf16(af1, bf0, acc[1][0], 0, 0, 0);
      acc[1][1] = __builtin_amdgcn_mfma_f32_32x32x16_bf16(af1, bf1, acc[1][1], 0, 0, 0);
    }
    __syncthreads();
  }

  const int vlim = eend - pos0;
#pragma unroll
  for (int i = 0; i < 2; ++i) {
#pragma unroll
    for (int r = 0; r < 16; ++r) {
      const int row = 64 * wr + 32 * i + (r & 3) + 8 * (r >> 2) + 4 * hi;
      if (row < vlim) {
        const int pos = pos0 + row;
        const float wt = wgt[pos];
        unsigned short* dst = opair + (size_t)pos * K_DIM + n0 + 64 * wc;
        dst[la]      = (unsigned short)f2bf(wt * acc[i][0][r]);
        dst[32 + la] = (unsigned short)f2bf(wt * acc[i][1][r]);
      }
    }
  }
}

// ---------------- combine: out[m] = opair[inv[2m]] + opair[inv[2m+1]] ----------------
__global__ void moe_combine(const unsigned short* __restrict__ opair,
                            const int* __restrict__ inv,
                            float* __restrict__ out) {
  const int m = blockIdx.x;
  const int t = threadIdx.x;  // 128 threads * 8 elems
  const int p0 = inv[2 * m], p1 = inv[2 * m + 1];
  const s16x8 a = *(const s16x8*)&opair[(size_t)p0 * K_DIM + t * 8];
  const s16x8 b = *(const s16x8*)&opair[(size_t)p1 * K_DIM + t * 8];
  float4 o0, o1;
  o0.x = bf2f((unsigned short)a[0]) + bf2f((unsigned short)b[0]);
  o0.y = bf2f((unsigned short)a[1]) + bf2f((unsigned short)b[1]);
  o0.z = bf2f((unsigned short)a[2]) + bf2f((unsigned short)b[2]);
  o0.w = bf2f((unsigned short)a[3]) + bf2f((unsigned short)b[3]);
  o1.x = bf2f((unsigned short)a[4]) + bf2f((unsigned short)b[4]);
  o1.y = bf2f((unsigned short)a[5]) + bf2f((unsigned short)b[5]);
  o1.z = bf2f((unsigned short)a[6]) + bf2f((unsigned short)b[6]);
  o1.w = bf2f((unsigned short)a[7]) + bf2f((unsigned short)b[7]);
  float4* dst = (float4*)(out + (size_t)m * K_DIM + t * 8);
  dst[0] = o0;
  dst[1] = o1;
}

__global__ void sentinel_k(float* o) { o[0] = 1.0e9f; }

extern "C" void kernel_launch(void* const* d_in, const int* in_sizes, int n_in,
                              void* d_out, int out_size, void* d_ws, size_t ws_size,
                              hipStream_t stream) {
  const float* hs = (const float*)d_in[0];
  const float* w1 = (const float*)d_in[1];
  const float* w2 = (const float*)d_in[2];
  const float* tw = (const float*)d_in[3];
  const int* ids = (const int*)d_in[4];
  float* out = (float*)d_out;

  char* p = (char*)d_ws;
  auto carve = [&](size_t bytes) {
    char* r = p;
    p += (bytes + 255) & ~(size_t)255;
    return r;
  };
  unsigned short* w1b = (unsigned short*)carve((size_t)E_NUM * N_DIM * K_DIM * 2);
  unsigned short* w2b = (unsigned short*)carve((size_t)E_NUM * K_DIM * HALF_N * 2);
  unsigned short* hsb = (unsigned short*)carve((size_t)(NPAIR + BM) * K_DIM * 2);
  unsigned short* h2  = (unsigned short*)carve((size_t)(NPAIR + BM) * HALF_N * 2);
  int*   tok  = (int*)carve(NPAIR * 4);
  float* wgt  = (float*)carve(NPAIR * 4);
  int*   inv  = (int*)carve(NPAIR * 4);
  int*   meta = (int*)carve(1024);
  int4*  desc = (int4*)carve(NDESC * sizeof(int4));
  size_t need = (size_t)(p - (char*)d_ws);

  // opair aliases hsb (hsb dead after gemm1; identical size NPAIR*K_DIM*2)
  unsigned short* opair = hsb;

  if (need > ws_size) {  // unmistakable failure mode if workspace is too small
    hipMemsetAsync(d_out, 0, (size_t)out_size * sizeof(float), stream);
    sentinel_k<<<1, 1, 0, stream>>>(out);
    return;
  }

  int* cnt  = meta;        // 8 ints
  int* fill = meta + 64;   // 8 ints
  int* offs = meta + 128;  // 9 ints

  hipMemsetAsync(meta, 0, 1024, stream);

  cvt_f32_bf16_k<<<2048, 256, 0, stream>>>(
      (const float4*)w1, (s16x4*)w1b, (int)((size_t)E_NUM * N_DIM * K_DIM / 4));
  cvt_f32_bf16_k<<<2048, 256, 0, stream>>>(
      (const float4*)w2, (s16x4*)w2b, (int)((size_t)E_NUM * K_DIM * HALF_N / 4));
  moe_count<<<NPAIR / 256, 256, 0, stream>>>(ids, cnt);
  moe_build<<<1, 64, 0, stream>>>(cnt, offs, desc);
  moe_scatter<<<NPAIR / 256, 256, 0, stream>>>(ids, tw, offs, fill, tok, wgt, inv);
  moe_gather<<<NPAIR, 128, 0, stream>>>(hs, tok, hsb);
  moe_gemm1<<<NHB1 * NDESC, 512, 0, stream>>>(hsb, w1b, desc, h2);
  moe_gemm2<<<NNB2 * NDESC, 512, 0, stream>>>(h2, w2b, desc, wgt, opair);
  moe_combine<<<M_TOK, 128, 0, stream>>>(opair, inv, out);
}

// Round 9
// 857.875 us; speedup vs baseline: 1.5942x; 1.5942x over previous
//
#include <hip/hip_runtime.h>
#include <hip/hip_bf16.h>

#define M_TOK 16384
#define K_DIM 1024
#define E_NUM 8
#define N_DIM 5632
#define HALF_N 2816
#define TOPK 2
#define NPAIR (M_TOK * TOPK)     // 32768
#define BM 128
#define BK 64
#define BH1 128                  // gemm1 h-cols per block
#define BN2 256                  // gemm2 k-cols per block
#define NDESC (NPAIR / BM + E_NUM)  // 264
#define NHB1 (HALF_N / BH1)      // 22
#define NNB2 (K_DIM / BN2)       // 4

typedef short s16x4 __attribute__((ext_vector_type(4)));
typedef short s16x8 __attribute__((ext_vector_type(8)));
typedef float f32x4 __attribute__((ext_vector_type(4)));

__device__ __forceinline__ short f2bf(float f) {
  union { __hip_bfloat16 h; short s; } c;
  c.h = __float2bfloat16(f);
  return c.s;
}

__device__ __forceinline__ float bf2f(unsigned short s) {
  union { float f; unsigned u; } c;
  c.u = ((unsigned)s) << 16;
  return c.f;
}

__device__ __forceinline__ void gload_lds16(const void* g, void* l) {
  __builtin_amdgcn_global_load_lds(
      (const __attribute__((address_space(1))) unsigned int*)g,
      (__attribute__((address_space(3))) unsigned int*)l, 16, 0, 0);
}

// bijective XCD-aware work remap (m204): consecutive work indices land on one XCD
__device__ __forceinline__ int xcd_work(int bid, int nwg) {
  const int xcd = bid & 7, loc = bid >> 3;
  const int q = nwg >> 3, r = nwg & 7;
  return (xcd < r ? xcd * (q + 1) : r * (q + 1) + (xcd - r) * q) + loc;
}

// ---------------- conversion ----------------
__global__ void cvt_f32_bf16_k(const float4* __restrict__ src,
                               s16x4* __restrict__ dst, int n4) {
  int i = blockIdx.x * blockDim.x + threadIdx.x;
  int stride = gridDim.x * blockDim.x;
  for (; i < n4; i += stride) {
    float4 f = src[i];
    s16x4 o = { f2bf(f.x), f2bf(f.y), f2bf(f.z), f2bf(f.w) };
    dst[i] = o;
  }
}

// ---------------- routing (two-level, ~1k global atomics total) ----------------
__global__ void moe_count(const int* __restrict__ ids, int* __restrict__ cnt) {
  const int p = blockIdx.x * 256 + threadIdx.x;
  const int e = ids[p];
  const int lane = threadIdx.x & 63;
  __shared__ int h[E_NUM];
  if (threadIdx.x < E_NUM) h[threadIdx.x] = 0;
  __syncthreads();
#pragma unroll
  for (int ex = 0; ex < E_NUM; ++ex) {
    unsigned long long m = __ballot(e == ex);
    if (lane == 0 && m) atomicAdd(&h[ex], __popcll(m));
  }
  __syncthreads();
  if (threadIdx.x < E_NUM) atomicAdd(&cnt[threadIdx.x], h[threadIdx.x]);
}

__global__ void moe_build(const int* __restrict__ cnt, int* __restrict__ offs,
                          int4* __restrict__ desc) {
  if (blockIdx.x == 0 && threadIdx.x == 0) {
    int o = 0, d = 0;
    for (int e = 0; e < E_NUM; ++e) {
      offs[e] = o;
      int end = o + cnt[e];
      for (int s = o; s < end; s += BM) desc[d++] = make_int4(e, s, end, 0);
      o = end;
    }
    offs[E_NUM] = o;
    while (d < NDESC) desc[d++] = make_int4(-1, 0, 0, 0);
  }
}

__global__ void moe_scatter(const int* __restrict__ ids, const float* __restrict__ tw,
                            const int* __restrict__ offs, int* __restrict__ fill,
                            int* __restrict__ tok, float* __restrict__ wgt,
                            int* __restrict__ inv) {
  const int p = blockIdx.x * 256 + threadIdx.x;
  const int e = ids[p];
  const int lane = threadIdx.x & 63;
  const int w = threadIdx.x >> 6;  // 0..3
  __shared__ int wcnt[4][E_NUM];
  __shared__ int wpre[4][E_NUM];
  __shared__ int base[E_NUM];
  const unsigned long long lt = (1ull << lane) - 1ull;
  int myrank = 0;
#pragma unroll
  for (int ex = 0; ex < E_NUM; ++ex) {
    unsigned long long m = __ballot(e == ex);
    if (e == ex) myrank = (int)__popcll(m & lt);
    if (lane == 0) wcnt[w][ex] = (int)__popcll(m);
  }
  __syncthreads();
  if (threadIdx.x < E_NUM) {
    const int ex = threadIdx.x;
    int s = 0;
#pragma unroll
    for (int ww = 0; ww < 4; ++ww) { wpre[ww][ex] = s; s += wcnt[ww][ex]; }
    base[ex] = atomicAdd(&fill[ex], s);
  }
  __syncthreads();
  const int pos = offs[e] + base[e] + wpre[w][e] + myrank;
  tok[pos] = p >> 1;
  wgt[pos] = tw[p];
  inv[p] = pos;
}

// gather hidden rows into expert-sorted order, fp32 -> bf16
__global__ void moe_gather(const float* __restrict__ hs, const int* __restrict__ tok,
                           unsigned short* __restrict__ hsb) {
  const int pos = blockIdx.x;
  const int m = tok[pos];
  const int t = threadIdx.x;  // 128 threads * 8 elems = 1024
  const float4* s = (const float4*)(hs + (size_t)m * K_DIM) + t * 2;
  const float4 a = s[0], b = s[1];
  s16x8 o = { f2bf(a.x), f2bf(a.y), f2bf(a.z), f2bf(a.w),
              f2bf(b.x), f2bf(b.y), f2bf(b.z), f2bf(b.w) };
  *(s16x8*)(hsb + (size_t)pos * K_DIM + t * 8) = o;
}

// ---------------- GEMM1: h2 = silu(A@Wg^T) * (A@Wu^T) ----------------
// round-7 proven kernel (2-barrier, T2 swizzle, gload_lds, 8 waves, 16x16 MFMA)
// with COL-MAJOR work decode: consecutive work on an XCD shares the 0.5 MB
// weight slab (L2-resident) and streams A-tiles (L3-resident) instead of the
// reverse -> staging loads hit L2, shrinking the barrier-drain stall.
__launch_bounds__(512)
__global__ void moe_gemm1(const unsigned short* __restrict__ hsb,
                          const unsigned short* __restrict__ w1b,
                          const int4* __restrict__ desc,
                          unsigned short* __restrict__ h2) {
  const int work = xcd_work(blockIdx.x, NHB1 * NDESC);
  const int di = work % NDESC;   // col-major: weight slab reused across di
  const int hb = work / NDESC;
  const int4 d = desc[di];
  const int e = d.x;
  if (e < 0) return;
  const int pos0 = d.y, eend = d.z;
  const int h0 = hb * BH1;

  __shared__ __align__(16) unsigned short As[BM * BK];    // 16 KB
  __shared__ __align__(16) unsigned short Gs[BH1 * BK];   // 16 KB
  __shared__ __align__(16) unsigned short Us[BH1 * BK];   // 16 KB

  const int tid = threadIdx.x;
  const int lane = tid & 63;
  const int wid = tid >> 6;     // 0..7
  const int wr = wid >> 2;      // 0..1 (64-row group)
  const int wc = wid & 3;       // 0..3 (32-col group)

  const unsigned short* Ab = hsb + (size_t)pos0 * K_DIM;
  const unsigned short* Gb = w1b + ((size_t)e * N_DIM + h0) * K_DIM;
  const unsigned short* Ub = Gb + (size_t)HALF_N * K_DIM;

  f32x4 accg[4][2], accu[4][2];
  const f32x4 z = {0.f, 0.f, 0.f, 0.f};
#pragma unroll
  for (int i = 0; i < 4; ++i)
#pragma unroll
    for (int j = 0; j < 2; ++j) { accg[i][j] = z; accu[i][j] = z; }

  const int lrow = lane >> 3;                   // 0..7 row within segment
  const int scol = ((lane & 7) ^ lrow) << 3;    // swizzled source chunk (shorts)
  const int fr = lane & 15;
  const int fq = lane >> 4;
  const int sw = fr & 7;                        // read-side row swizzle key

  for (int kt = 0; kt < K_DIM / BK; ++kt) {
    const int k0 = kt * BK;
#pragma unroll
    for (int c = 0; c < 2; ++c) {
      const int seg = c * 8 + wid;              // 0..15
      const int row = seg * 8 + lrow;
      gload_lds16(Ab + (size_t)row * K_DIM + k0 + scol, &As[seg * 512]);
      gload_lds16(Gb + (size_t)row * K_DIM + k0 + scol, &Gs[seg * 512]);
      gload_lds16(Ub + (size_t)row * K_DIM + k0 + scol, &Us[seg * 512]);
    }
    __syncthreads();
#pragma unroll
    for (int s = 0; s < 2; ++s) {
      const int coff = (((s * 4 + fq) ^ sw) << 3);
      s16x8 af[4];
#pragma unroll
      for (int i = 0; i < 4; ++i)
        af[i] = *(const s16x8*)&As[(64 * wr + 16 * i + fr) * BK + coff];
      s16x8 gf[2], uf[2];
#pragma unroll
      for (int j = 0; j < 2; ++j) {
        const int hr = (32 * wc + 16 * j + fr) * BK + coff;
        gf[j] = *(const s16x8*)&Gs[hr];
        uf[j] = *(const s16x8*)&Us[hr];
      }
#pragma unroll
      for (int i = 0; i < 4; ++i)
#pragma unroll
        for (int j = 0; j < 2; ++j) {
          accg[i][j] = __builtin_amdgcn_mfma_f32_16x16x32_bf16(af[i], gf[j], accg[i][j], 0, 0, 0);
          accu[i][j] = __builtin_amdgcn_mfma_f32_16x16x32_bf16(af[i], uf[j], accu[i][j], 0, 0, 0);
        }
    }
    __syncthreads();
  }

  const int vlim = eend - pos0;
#pragma unroll
  for (int i = 0; i < 4; ++i) {
#pragma unroll
    for (int rr = 0; rr < 4; ++rr) {
      const int row = 64 * wr + 16 * i + fq * 4 + rr;
      if (row < vlim) {
        unsigned short* dst = h2 + (size_t)(pos0 + row) * HALF_N + h0 + 32 * wc;
#pragma unroll
        for (int j = 0; j < 2; ++j) {
          const float g = accg[i][j][rr];
          const float u = accu[i][j][rr];
          const float sg = g / (1.0f + __expf(-g));
          dst[16 * j + fr] = (unsigned short)f2bf(sg * u);
        }
      }
    }
  }
}

// ---------------- GEMM2: opair[pos] = wgt[pos] * (h2[pos] @ W2^T) ----------------
// round-7 proven kernel with col-major work decode (1.4 MB B slab L2-resident).
__launch_bounds__(512)
__global__ void moe_gemm2(const unsigned short* __restrict__ h2,
                          const unsigned short* __restrict__ w2b,
                          const int4* __restrict__ desc,
                          const float* __restrict__ wgt,
                          unsigned short* __restrict__ opair) {
  const int work = xcd_work(blockIdx.x, NNB2 * NDESC);
  const int di = work % NDESC;   // col-major: B slab reused across di
  const int nb = work / NDESC;
  const int4 d = desc[di];
  const int e = d.x;
  if (e < 0) return;
  const int pos0 = d.y, eend = d.z;
  const int n0 = nb * BN2;

  __shared__ __align__(16) unsigned short As[BM * BK];    // 16 KB
  __shared__ __align__(16) unsigned short Bs[BN2 * BK];   // 32 KB

  const int tid = threadIdx.x;
  const int lane = tid & 63;
  const int wid = tid >> 6;     // 0..7
  const int wr = wid >> 2;      // 0..1 (64-row group)
  const int wc = wid & 3;       // 0..3 (64-col group)

  const unsigned short* Ab = h2 + (size_t)pos0 * HALF_N;
  const unsigned short* Bb = w2b + ((size_t)e * K_DIM + n0) * HALF_N;

  f32x4 acc[4][4];
  const f32x4 z = {0.f, 0.f, 0.f, 0.f};
#pragma unroll
  for (int i = 0; i < 4; ++i)
#pragma unroll
    for (int j = 0; j < 4; ++j) acc[i][j] = z;

  const int lrow = lane >> 3;
  const int scol = ((lane & 7) ^ lrow) << 3;
  const int fr = lane & 15;
  const int fq = lane >> 4;
  const int sw = fr & 7;

  for (int ht = 0; ht < HALF_N / BK; ++ht) {   // 44
    const int k0 = ht * BK;
#pragma unroll
    for (int c = 0; c < 2; ++c) {
      const int seg = c * 8 + wid;             // 0..15
      const int row = seg * 8 + lrow;
      gload_lds16(Ab + (size_t)row * HALF_N + k0 + scol, &As[seg * 512]);
    }
#pragma unroll
    for (int c = 0; c < 4; ++c) {
      const int seg = c * 8 + wid;             // 0..31
      const int row = seg * 8 + lrow;
      gload_lds16(Bb + (size_t)row * HALF_N + k0 + scol, &Bs[seg * 512]);
    }
    __syncthreads();
#pragma unroll
    for (int s = 0; s < 2; ++s) {
      const int coff = (((s * 4 + fq) ^ sw) << 3);
      s16x8 af[4], bf[4];
#pragma unroll
      for (int i = 0; i < 4; ++i)
        af[i] = *(const s16x8*)&As[(64 * wr + 16 * i + fr) * BK + coff];
#pragma unroll
      for (int j = 0; j < 4; ++j)
        bf[j] = *(const s16x8*)&Bs[(64 * wc + 16 * j + fr) * BK + coff];
#pragma unroll
      for (int i = 0; i < 4; ++i)
#pragma unroll
        for (int j = 0; j < 4; ++j)
          acc[i][j] = __builtin_amdgcn_mfma_f32_16x16x32_bf16(af[i], bf[j], acc[i][j], 0, 0, 0);
    }
    __syncthreads();
  }

  const int vlim = eend - pos0;
#pragma unroll
  for (int i = 0; i < 4; ++i) {
#pragma unroll
    for (int rr = 0; rr < 4; ++rr) {
      const int row = 64 * wr + 16 * i + fq * 4 + rr;
      if (row < vlim) {
        const int pos = pos0 + row;
        const float wt = wgt[pos];
        unsigned short* dst = opair + (size_t)pos * K_DIM + n0 + 64 * wc;
#pragma unroll
        for (int j = 0; j < 4; ++j)
          dst[16 * j + fr] = (unsigned short)f2bf(wt * acc[i][j][rr]);
      }
    }
  }
}

// ---------------- combine: out[m] = opair[inv[2m]] + opair[inv[2m+1]] ----------------
__global__ void moe_combine(const unsigned short* __restrict__ opair,
                            const int* __restrict__ inv,
                            float* __restrict__ out) {
  const int m = blockIdx.x;
  const int t = threadIdx.x;  // 128 threads * 8 elems
  const int p0 = inv[2 * m], p1 = inv[2 * m + 1];
  const s16x8 a = *(const s16x8*)&opair[(size_t)p0 * K_DIM + t * 8];
  const s16x8 b = *(const s16x8*)&opair[(size_t)p1 * K_DIM + t * 8];
  float4 o0, o1;
  o0.x = bf2f((unsigned short)a[0]) + bf2f((unsigned short)b[0]);
  o0.y = bf2f((unsigned short)a[1]) + bf2f((unsigned short)b[1]);
  o0.z = bf2f((unsigned short)a[2]) + bf2f((unsigned short)b[2]);
  o0.w = bf2f((unsigned short)a[3]) + bf2f((unsigned short)b[3]);
  o1.x = bf2f((unsigned short)a[4]) + bf2f((unsigned short)b[4]);
  o1.y = bf2f((unsigned short)a[5]) + bf2f((unsigned short)b[5]);
  o1.z = bf2f((unsigned short)a[6]) + bf2f((unsigned short)b[6]);
  o1.w = bf2f((unsigned short)a[7]) + bf2f((unsigned short)b[7]);
  float4* dst = (float4*)(out + (size_t)m * K_DIM + t * 8);
  dst[0] = o0;
  dst[1] = o1;
}

__global__ void sentinel_k(float* o) { o[0] = 1.0e9f; }

extern "C" void kernel_launch(void* const* d_in, const int* in_sizes, int n_in,
                              void* d_out, int out_size, void* d_ws, size_t ws_size,
                              hipStream_t stream) {
  const float* hs = (const float*)d_in[0];
  const float* w1 = (const float*)d_in[1];
  const float* w2 = (const float*)d_in[2];
  const float* tw = (const float*)d_in[3];
  const int* ids = (const int*)d_in[4];
  float* out = (float*)d_out;

  char* p = (char*)d_ws;
  auto carve = [&](size_t bytes) {
    char* r = p;
    p += (bytes + 255) & ~(size_t)255;
    return r;
  };
  unsigned short* w1b = (unsigned short*)carve((size_t)E_NUM * N_DIM * K_DIM * 2);
  unsigned short* w2b = (unsigned short*)carve((size_t)E_NUM * K_DIM * HALF_N * 2);
  unsigned short* hsb = (unsigned short*)carve((size_t)(NPAIR + BM) * K_DIM * 2);
  unsigned short* h2  = (unsigned short*)carve((size_t)(NPAIR + BM) * HALF_N * 2);
  int*   tok  = (int*)carve(NPAIR * 4);
  float* wgt  = (float*)carve(NPAIR * 4);
  int*   inv  = (int*)carve(NPAIR * 4);
  int*   meta = (int*)carve(1024);
  int4*  desc = (int4*)carve(NDESC * sizeof(int4));
  size_t need = (size_t)(p - (char*)d_ws);

  // opair aliases hsb (hsb dead after gemm1; identical size NPAIR*K_DIM*2)
  unsigned short* opair = hsb;

  if (need > ws_size) {  // unmistakable failure mode if workspace is too small
    hipMemsetAsync(d_out, 0, (size_t)out_size * sizeof(float), stream);
    sentinel_k<<<1, 1, 0, stream>>>(out);
    return;
  }

  int* cnt  = meta;        // 8 ints
  int* fill = meta + 64;   // 8 ints
  int* offs = meta + 128;  // 9 ints

  hipMemsetAsync(meta, 0, 1024, stream);

  cvt_f32_bf16_k<<<2048, 256, 0, stream>>>(
      (const float4*)w1, (s16x4*)w1b, (int)((size_t)E_NUM * N_DIM * K_DIM / 4));
  cvt_f32_bf16_k<<<2048, 256, 0, stream>>>(
      (const float4*)w2, (s16x4*)w2b, (int)((size_t)E_NUM * K_DIM * HALF_N / 4));
  moe_count<<<NPAIR / 256, 256, 0, stream>>>(ids, cnt);
  moe_build<<<1, 64, 0, stream>>>(cnt, offs, desc);
  moe_scatter<<<NPAIR / 256, 256, 0, stream>>>(ids, tw, offs, fill, tok, wgt, inv);
  moe_gather<<<NPAIR, 128, 0, stream>>>(hs, tok, hsb);
  moe_gemm1<<<NHB1 * NDESC, 512, 0, stream>>>(hsb, w1b, desc, h2);
  moe_gemm2<<<NNB2 * NDESC, 512, 0, stream>>>(h2, w2b, desc, wgt, opair);
  moe_combine<<<M_TOK, 128, 0, stream>>>(opair, inv, out);
}

// Round 11
// 787.328 us; speedup vs baseline: 1.7371x; 1.0896x over previous
//
#include <hip/hip_runtime.h>
#include <hip/hip_bf16.h>

#define M_TOK 16384
#define K_DIM 1024
#define E_NUM 8
#define N_DIM 5632
#define HALF_N 2816
#define TOPK 2
#define NPAIR (M_TOK * TOPK)     // 32768
#define BM 128
#define BK 64
#define BH1 128                  // gemm1 h-cols per block
#define BN2 256                  // gemm2 k-cols per block
#define NDESC (NPAIR / BM + E_NUM)  // 264
#define NHB1 (HALF_N / BH1)      // 22
#define NNB2 (K_DIM / BN2)       // 4

typedef short s16x4 __attribute__((ext_vector_type(4)));
typedef short s16x8 __attribute__((ext_vector_type(8)));
typedef float f32x4 __attribute__((ext_vector_type(4)));

__device__ __forceinline__ short f2bf(float f) {
  union { __hip_bfloat16 h; short s; } c;
  c.h = __float2bfloat16(f);
  return c.s;
}

__device__ __forceinline__ float bf2f(unsigned short s) {
  union { float f; unsigned u; } c;
  c.u = ((unsigned)s) << 16;
  return c.f;
}

__device__ __forceinline__ void gload_lds16(const void* g, void* l) {
  __builtin_amdgcn_global_load_lds(
      (const __attribute__((address_space(1))) unsigned int*)g,
      (__attribute__((address_space(3))) unsigned int*)l, 16, 0, 0);
}

// bijective XCD-aware work remap (m204): consecutive work indices land on one XCD
__device__ __forceinline__ int xcd_work(int bid, int nwg) {
  const int xcd = bid & 7, loc = bid >> 3;
  const int q = nwg >> 3, r = nwg & 7;
  return (xcd < r ? xcd * (q + 1) : r * (q + 1) + (xcd - r) * q) + loc;
}

// ---------------- conversion ----------------
__global__ void cvt_f32_bf16_k(const float4* __restrict__ src,
                               s16x4* __restrict__ dst, int n4) {
  int i = blockIdx.x * blockDim.x + threadIdx.x;
  int stride = gridDim.x * blockDim.x;
  for (; i < n4; i += stride) {
    float4 f = src[i];
    s16x4 o = { f2bf(f.x), f2bf(f.y), f2bf(f.z), f2bf(f.w) };
    dst[i] = o;
  }
}

// ---------------- routing (two-level, ~1k global atomics total) ----------------
__global__ void moe_count(const int* __restrict__ ids, int* __restrict__ cnt) {
  const int p = blockIdx.x * 256 + threadIdx.x;
  const int e = ids[p];
  const int lane = threadIdx.x & 63;
  __shared__ int h[E_NUM];
  if (threadIdx.x < E_NUM) h[threadIdx.x] = 0;
  __syncthreads();
#pragma unroll
  for (int ex = 0; ex < E_NUM; ++ex) {
    unsigned long long m = __ballot(e == ex);
    if (lane == 0 && m) atomicAdd(&h[ex], __popcll(m));
  }
  __syncthreads();
  if (threadIdx.x < E_NUM) atomicAdd(&cnt[threadIdx.x], h[threadIdx.x]);
}

__global__ void moe_build(const int* __restrict__ cnt, int* __restrict__ offs,
                          int4* __restrict__ desc) {
  if (blockIdx.x == 0 && threadIdx.x == 0) {
    int o = 0, d = 0;
    for (int e = 0; e < E_NUM; ++e) {
      offs[e] = o;
      int end = o + cnt[e];
      for (int s = o; s < end; s += BM) desc[d++] = make_int4(e, s, end, 0);
      o = end;
    }
    offs[E_NUM] = o;
    while (d < NDESC) desc[d++] = make_int4(-1, 0, 0, 0);
  }
}

__global__ void moe_scatter(const int* __restrict__ ids, const float* __restrict__ tw,
                            const int* __restrict__ offs, int* __restrict__ fill,
                            int* __restrict__ tok, float* __restrict__ wgt,
                            int* __restrict__ inv) {
  const int p = blockIdx.x * 256 + threadIdx.x;
  const int e = ids[p];
  const int lane = threadIdx.x & 63;
  const int w = threadIdx.x >> 6;  // 0..3
  __shared__ int wcnt[4][E_NUM];
  __shared__ int wpre[4][E_NUM];
  __shared__ int base[E_NUM];
  const unsigned long long lt = (1ull << lane) - 1ull;
  int myrank = 0;
#pragma unroll
  for (int ex = 0; ex < E_NUM; ++ex) {
    unsigned long long m = __ballot(e == ex);
    if (e == ex) myrank = (int)__popcll(m & lt);
    if (lane == 0) wcnt[w][ex] = (int)__popcll(m);
  }
  __syncthreads();
  if (threadIdx.x < E_NUM) {
    const int ex = threadIdx.x;
    int s = 0;
#pragma unroll
    for (int ww = 0; ww < 4; ++ww) { wpre[ww][ex] = s; s += wcnt[ww][ex]; }
    base[ex] = atomicAdd(&fill[ex], s);
  }
  __syncthreads();
  const int pos = offs[e] + base[e] + wpre[w][e] + myrank;
  tok[pos] = p >> 1;
  wgt[pos] = tw[p];
  inv[p] = pos;
}

// gather hidden rows into expert-sorted order, fp32 -> bf16
__global__ void moe_gather(const float* __restrict__ hs, const int* __restrict__ tok,
                           unsigned short* __restrict__ hsb) {
  const int pos = blockIdx.x;
  const int m = tok[pos];
  const int t = threadIdx.x;  // 128 threads * 8 elems = 1024
  const float4* s = (const float4*)(hs + (size_t)m * K_DIM) + t * 2;
  const float4 a = s[0], b = s[1];
  s16x8 o = { f2bf(a.x), f2bf(a.y), f2bf(a.z), f2bf(a.w),
              f2bf(b.x), f2bf(b.y), f2bf(b.z), f2bf(b.w) };
  *(s16x8*)(hsb + (size_t)pos * K_DIM + t * 8) = o;
}

// ---------------- GEMM1: h2 = silu(A@Wg^T) * (A@Wu^T) ----------------
// round-7 proven kernel (desc-major decode). NEW: nontemporal h2 stores so the
// 180 MB write stream doesn't evict the L2/L3 read set (A-tiles + weights) --
// targets the 9x FETCH over-read (1.03 GB vs ~115 MB ideal).
__launch_bounds__(512)
__global__ void moe_gemm1(const unsigned short* __restrict__ hsb,
                          const unsigned short* __restrict__ w1b,
                          const int4* __restrict__ desc,
                          unsigned short* __restrict__ h2) {
  const int work = xcd_work(blockIdx.x, NHB1 * NDESC);
  const int di = work / NHB1;    // desc-major (proven r7 mapping)
  const int hb = work - di * NHB1;
  const int4 d = desc[di];
  const int e = d.x;
  if (e < 0) return;
  const int pos0 = d.y, eend = d.z;
  const int h0 = hb * BH1;

  __shared__ __align__(16) unsigned short As[BM * BK];    // 16 KB
  __shared__ __align__(16) unsigned short Gs[BH1 * BK];   // 16 KB
  __shared__ __align__(16) unsigned short Us[BH1 * BK];   // 16 KB

  const int tid = threadIdx.x;
  const int lane = tid & 63;
  const int wid = tid >> 6;     // 0..7
  const int wr = wid >> 2;      // 0..1 (64-row group)
  const int wc = wid & 3;       // 0..3 (32-col group)

  const unsigned short* Ab = hsb + (size_t)pos0 * K_DIM;
  const unsigned short* Gb = w1b + ((size_t)e * N_DIM + h0) * K_DIM;
  const unsigned short* Ub = Gb + (size_t)HALF_N * K_DIM;

  f32x4 accg[4][2], accu[4][2];
  const f32x4 z = {0.f, 0.f, 0.f, 0.f};
#pragma unroll
  for (int i = 0; i < 4; ++i)
#pragma unroll
    for (int j = 0; j < 2; ++j) { accg[i][j] = z; accu[i][j] = z; }

  const int lrow = lane >> 3;                   // 0..7 row within segment
  const int scol = ((lane & 7) ^ lrow) << 3;    // swizzled source chunk (shorts)
  const int fr = lane & 15;
  const int fq = lane >> 4;
  const int sw = fr & 7;                        // read-side row swizzle key

  for (int kt = 0; kt < K_DIM / BK; ++kt) {
    const int k0 = kt * BK;
#pragma unroll
    for (int c = 0; c < 2; ++c) {
      const int seg = c * 8 + wid;              // 0..15
      const int row = seg * 8 + lrow;
      gload_lds16(Ab + (size_t)row * K_DIM + k0 + scol, &As[seg * 512]);
      gload_lds16(Gb + (size_t)row * K_DIM + k0 + scol, &Gs[seg * 512]);
      gload_lds16(Ub + (size_t)row * K_DIM + k0 + scol, &Us[seg * 512]);
    }
    __syncthreads();
#pragma unroll
    for (int s = 0; s < 2; ++s) {
      const int coff = (((s * 4 + fq) ^ sw) << 3);
      s16x8 af[4];
#pragma unroll
      for (int i = 0; i < 4; ++i)
        af[i] = *(const s16x8*)&As[(64 * wr + 16 * i + fr) * BK + coff];
      s16x8 gf[2], uf[2];
#pragma unroll
      for (int j = 0; j < 2; ++j) {
        const int hr = (32 * wc + 16 * j + fr) * BK + coff;
        gf[j] = *(const s16x8*)&Gs[hr];
        uf[j] = *(const s16x8*)&Us[hr];
      }
#pragma unroll
      for (int i = 0; i < 4; ++i)
#pragma unroll
        for (int j = 0; j < 2; ++j) {
          accg[i][j] = __builtin_amdgcn_mfma_f32_16x16x32_bf16(af[i], gf[j], accg[i][j], 0, 0, 0);
          accu[i][j] = __builtin_amdgcn_mfma_f32_16x16x32_bf16(af[i], uf[j], accu[i][j], 0, 0, 0);
        }
    }
    __syncthreads();
  }

  const int vlim = eend - pos0;
#pragma unroll
  for (int i = 0; i < 4; ++i) {
#pragma unroll
    for (int rr = 0; rr < 4; ++rr) {
      const int row = 64 * wr + 16 * i + fq * 4 + rr;
      if (row < vlim) {
        unsigned short* dst = h2 + (size_t)(pos0 + row) * HALF_N + h0 + 32 * wc;
#pragma unroll
        for (int j = 0; j < 2; ++j) {
          const float g = accg[i][j][rr];
          const float u = accu[i][j][rr];
          const float sg = g / (1.0f + __expf(-g));
          __builtin_nontemporal_store((unsigned short)f2bf(sg * u), dst + 16 * j + fr);
        }
      }
    }
  }
}

// ---------------- GEMM2: opair[pos] = wgt[pos] * (h2[pos] @ W2^T) ----------------
// round-7 proven kernel, desc-major decode. opair stores stay normal (combine
// reads them right after -> L3 residency is useful).
__launch_bounds__(512)
__global__ void moe_gemm2(const unsigned short* __restrict__ h2,
                          const unsigned short* __restrict__ w2b,
                          const int4* __restrict__ desc,
                          const float* __restrict__ wgt,
                          unsigned short* __restrict__ opair) {
  const int work = xcd_work(blockIdx.x, NNB2 * NDESC);
  const int di = work >> 2;      // desc-major (proven r7 mapping)
  const int nb = work & 3;
  const int4 d = desc[di];
  const int e = d.x;
  if (e < 0) return;
  const int pos0 = d.y, eend = d.z;
  const int n0 = nb * BN2;

  __shared__ __align__(16) unsigned short As[BM * BK];    // 16 KB
  __shared__ __align__(16) unsigned short Bs[BN2 * BK];   // 32 KB

  const int tid = threadIdx.x;
  const int lane = tid & 63;
  const int wid = tid >> 6;     // 0..7
  const int wr = wid >> 2;      // 0..1 (64-row group)
  const int wc = wid & 3;       // 0..3 (64-col group)

  const unsigned short* Ab = h2 + (size_t)pos0 * HALF_N;
  const unsigned short* Bb = w2b + ((size_t)e * K_DIM + n0) * HALF_N;

  f32x4 acc[4][4];
  const f32x4 z = {0.f, 0.f, 0.f, 0.f};
#pragma unroll
  for (int i = 0; i < 4; ++i)
#pragma unroll
    for (int j = 0; j < 4; ++j) acc[i][j] = z;

  const int lrow = lane >> 3;
  const int scol = ((lane & 7) ^ lrow) << 3;
  const int fr = lane & 15;
  const int fq = lane >> 4;
  const int sw = fr & 7;

  for (int ht = 0; ht < HALF_N / BK; ++ht) {   // 44
    const int k0 = ht * BK;
#pragma unroll
    for (int c = 0; c < 2; ++c) {
      const int seg = c * 8 + wid;             // 0..15
      const int row = seg * 8 + lrow;
      gload_lds16(Ab + (size_t)row * HALF_N + k0 + scol, &As[seg * 512]);
    }
#pragma unroll
    for (int c = 0; c < 4; ++c) {
      const int seg = c * 8 + wid;             // 0..31
      const int row = seg * 8 + lrow;
      gload_lds16(Bb + (size_t)row * HALF_N + k0 + scol, &Bs[seg * 512]);
    }
    __syncthreads();
#pragma unroll
    for (int s = 0; s < 2; ++s) {
      const int coff = (((s * 4 + fq) ^ sw) << 3);
      s16x8 af[4], bf[4];
#pragma unroll
      for (int i = 0; i < 4; ++i)
        af[i] = *(const s16x8*)&As[(64 * wr + 16 * i + fr) * BK + coff];
#pragma unroll
      for (int j = 0; j < 4; ++j)
        bf[j] = *(const s16x8*)&Bs[(64 * wc + 16 * j + fr) * BK + coff];
#pragma unroll
      for (int i = 0; i < 4; ++i)
#pragma unroll
        for (int j = 0; j < 4; ++j)
          acc[i][j] = __builtin_amdgcn_mfma_f32_16x16x32_bf16(af[i], bf[j], acc[i][j], 0, 0, 0);
    }
    __syncthreads();
  }

  const int vlim = eend - pos0;
#pragma unroll
  for (int i = 0; i < 4; ++i) {
#pragma unroll
    for (int rr = 0; rr < 4; ++rr) {
      const int row = 64 * wr + 16 * i + fq * 4 + rr;
      if (row < vlim) {
        const int pos = pos0 + row;
        const float wt = wgt[pos];
        unsigned short* dst = opair + (size_t)pos * K_DIM + n0 + 64 * wc;
#pragma unroll
        for (int j = 0; j < 4; ++j)
          dst[16 * j + fr] = (unsigned short)f2bf(wt * acc[i][j][rr]);
      }
    }
  }
}

// ---------------- combine: out[m] = opair[inv[2m]] + opair[inv[2m+1]] ----------------
__global__ void moe_combine(const unsigned short* __restrict__ opair,
                            const int* __restrict__ inv,
                            float* __restrict__ out) {
  const int m = blockIdx.x;
  const int t = threadIdx.x;  // 128 threads * 8 elems
  const int p0 = inv[2 * m], p1 = inv[2 * m + 1];
  const s16x8 a = *(const s16x8*)&opair[(size_t)p0 * K_DIM + t * 8];
  const s16x8 b = *(const s16x8*)&opair[(size_t)p1 * K_DIM + t * 8];
  f32x4 o0, o1;
  o0[0] = bf2f((unsigned short)a[0]) + bf2f((unsigned short)b[0]);
  o0[1] = bf2f((unsigned short)a[1]) + bf2f((unsigned short)b[1]);
  o0[2] = bf2f((unsigned short)a[2]) + bf2f((unsigned short)b[2]);
  o0[3] = bf2f((unsigned short)a[3]) + bf2f((unsigned short)b[3]);
  o1[0] = bf2f((unsigned short)a[4]) + bf2f((unsigned short)b[4]);
  o1[1] = bf2f((unsigned short)a[5]) + bf2f((unsigned short)b[5]);
  o1[2] = bf2f((unsigned short)a[6]) + bf2f((unsigned short)b[6]);
  o1[3] = bf2f((unsigned short)a[7]) + bf2f((unsigned short)b[7]);
  f32x4* dst = (f32x4*)(out + (size_t)m * K_DIM + t * 8);
  __builtin_nontemporal_store(o0, dst);       // final output, never re-read
  __builtin_nontemporal_store(o1, dst + 1);
}

__global__ void sentinel_k(float* o) { o[0] = 1.0e9f; }

extern "C" void kernel_launch(void* const* d_in, const int* in_sizes, int n_in,
                              void* d_out, int out_size, void* d_ws, size_t ws_size,
                              hipStream_t stream) {
  const float* hs = (const float*)d_in[0];
  const float* w1 = (const float*)d_in[1];
  const float* w2 = (const float*)d_in[2];
  const float* tw = (const float*)d_in[3];
  const int* ids = (const int*)d_in[4];
  float* out = (float*)d_out;

  char* p = (char*)d_ws;
  auto carve = [&](size_t bytes) {
    char* r = p;
    p += (bytes + 255) & ~(size_t)255;
    return r;
  };
  unsigned short* w1b = (unsigned short*)carve((size_t)E_NUM * N_DIM * K_DIM * 2);
  unsigned short* w2b = (unsigned short*)carve((size_t)E_NUM * K_DIM * HALF_N * 2);
  unsigned short* hsb = (unsigned short*)carve((size_t)(NPAIR + BM) * K_DIM * 2);
  unsigned short* h2  = (unsigned short*)carve((size_t)(NPAIR + BM) * HALF_N * 2);
  int*   tok  = (int*)carve(NPAIR * 4);
  float* wgt  = (float*)carve(NPAIR * 4);
  int*   inv  = (int*)carve(NPAIR * 4);
  int*   meta = (int*)carve(1024);
  int4*  desc = (int4*)carve(NDESC * sizeof(int4));
  size_t need = (size_t)(p - (char*)d_ws);

  // opair aliases hsb (hsb dead after gemm1; identical size NPAIR*K_DIM*2)
  unsigned short* opair = hsb;

  if (need > ws_size) {  // unmistakable failure mode if workspace is too small
    hipMemsetAsync(d_out, 0, (size_t)out_size * sizeof(float), stream);
    sentinel_k<<<1, 1, 0, stream>>>(out);
    return;
  }

  int* cnt  = meta;        // 8 ints
  int* fill = meta + 64;   // 8 ints
  int* offs = meta + 128;  // 9 ints

  hipMemsetAsync(meta, 0, 1024, stream);

  cvt_f32_bf16_k<<<2048, 256, 0, stream>>>(
      (const float4*)w1, (s16x4*)w1b, (int)((size_t)E_NUM * N_DIM * K_DIM / 4));
  cvt_f32_bf16_k<<<2048, 256, 0, stream>>>(
      (const float4*)w2, (s16x4*)w2b, (int)((size_t)E_NUM * K_DIM * HALF_N / 4));
  moe_count<<<NPAIR / 256, 256, 0, stream>>>(ids, cnt);
  moe_build<<<1, 64, 0, stream>>>(cnt, offs, desc);
  moe_scatter<<<NPAIR / 256, 256, 0, stream>>>(ids, tw, offs, fill, tok, wgt, inv);
  moe_gather<<<NPAIR, 128, 0, stream>>>(hs, tok, hsb);
  moe_gemm1<<<NHB1 * NDESC, 512, 0, stream>>>(hsb, w1b, desc, h2);
  moe_gemm2<<<NNB2 * NDESC, 512, 0, stream>>>(h2, w2b, desc, wgt, opair);
  moe_combine<<<M_TOK, 128, 0, stream>>>(opair, inv, out);
}